// Round 6
// baseline (83.521 us; speedup 1.0000x reference)
//
#include <hip/hip_runtime.h>
#include <hip/hip_bf16.h>

#define N_ROWS 8192
#define DIM 256
#define NANCH 64
#define NVIEW 128
#define APS 16      // anchors per strip
#define NPART 8     // column partitions (4 strips x 2 halves)

typedef __attribute__((ext_vector_type(8))) short bf16x8;
typedef __attribute__((ext_vector_type(4))) float f32x4;
typedef __attribute__((ext_vector_type(16))) float f32x16;
typedef __attribute__((ext_vector_type(4))) float float4v;
typedef __attribute__((ext_vector_type(4))) unsigned short ushort4v;

__device__ __forceinline__ unsigned short f2bf(float x) {
  union { float f; unsigned int u; } c; c.f = x;
  unsigned int u = c.u;
  unsigned int r = (u + 0x7fffu + ((u >> 16) & 1u)) >> 16;
  return (unsigned short)r;
}

__device__ __forceinline__ float bf2f(unsigned short b) {
  union { unsigned int u; float f; } c; c.u = ((unsigned int)b) << 16;
  return c.f;
}

__device__ __forceinline__ void gload_lds16(const void* g, void* l) {
  __builtin_amdgcn_global_load_lds(
      (const __attribute__((address_space(1))) unsigned int*)g,
      (__attribute__((address_space(3))) unsigned int*)l, 16, 0, 0);
}

// fp32 -> bf16 with 1/sqrt(T) prescale, fused with per-row squared-norm
// (= the Gram diagonal = the row max of the logits). One wave per row.
__global__ void cast_diag_kernel(const float4v* __restrict__ in,
                                 ushort4v* __restrict__ out,
                                 float* __restrict__ diag) {
  const int w = threadIdx.x >> 6;
  const int l = threadIdx.x & 63;
  const int row = blockIdx.x * 4 + w;
  const float s = 3.16227766016838f; // 1/sqrt(0.1)
  float4v v = in[row * 64 + l];
  ushort4v o;
  o.x = f2bf(v.x * s);
  o.y = f2bf(v.y * s);
  o.z = f2bf(v.z * s);
  o.w = f2bf(v.w * s);
  out[row * 64 + l] = o;
  float c0 = bf2f(o.x), c1 = bf2f(o.y), c2 = bf2f(o.z), c3 = bf2f(o.w);
  float ss = c0 * c0 + c1 * c1 + c2 * c2 + c3 * c3;
#pragma unroll
  for (int st = 1; st < 64; st <<= 1) ss += __shfl_xor(ss, st);
  if (l == 0) diag[row] = ss;
}

// -------- Kernel 2: negative-exp-sum partials over (128 rows x 1024 cols).
// grid = 64 row-blocks x 8 col-partitions. 8 waves = 4 row-groups x 2
// col-groups, 512 threads, 2 blocks/CU. 32x32x16 MFMA. B half-anchor tiles
// (64 cols x 256 k) staged in LDS in k-major fragment-linear layout
// [kh 0..31][col 0..63][16B]: each quarter-wave's ds_read_b128 is 16
// consecutive 16B chunks = all 32 banks exactly once -> zero conflicts.
// Row max is KNOWN (= diag): partials combine by pure addition.
__global__ __launch_bounds__(512, 4) void pcl_negsum(
    const unsigned short* __restrict__ Xb, const int* __restrict__ labels,
    const float* __restrict__ diag, float* __restrict__ ns_partial) {
  const int rb = blockIdx.x & 63;       // row anchor (128 rows, uniform label)
  const int part = blockIdx.x >> 6;     // 0..7
  const int strip = part >> 1;          // anchors strip*16 .. +15
  const int half = part & 1;            // 64-col half within each anchor
  const int tid = threadIdx.x;
  const int wid = tid >> 6;             // 0..7
  const int lane = tid & 63;
  const int l31 = lane & 31;
  const int khalf = lane >> 5;          // k-half within fragment
  const int rg = wid >> 1;              // row group (32 rows)
  const int cg = wid & 1;               // col group (32 cols)

  __shared__ unsigned short buf[2][64 * DIM];  // 2 x 32 KB, k-major layout
  __shared__ float sns[8][32];
  __shared__ float sdiag[128];
  __shared__ int slab[NANCH];

  if (tid < NANCH) slab[tid] = labels[tid];
  if (tid >= 128 && tid < 256) sdiag[tid - 128] = diag[rb * 128 + tid - 128];
  __syncthreads();
  const int myLab = slab[rb];

  // A fragments (32x32x16): lane holds row rg*32 + l31, k = ks*16 + khalf*8..+8.
  bf16x8 afrag[16];
#pragma unroll
  for (int ks = 0; ks < 16; ++ks) {
    const unsigned short* p =
        Xb + (size_t)(rb * 128 + rg * 32 + l31) * DIM + ks * 16 + khalf * 8;
    afrag[ks] = *(const bf16x8*)p;
    asm volatile("" : "+v"(afrag[ks]));  // def-pin: forbid remat
  }

  // Wave-uniform skip threshold: min diag over this wave's 32 rows - 40.
  float thr;
  {
    float d = sdiag[rg * 32 + l31];
#pragma unroll
    for (int st = 1; st < 32; st <<= 1) d = fminf(d, __shfl_xor(d, st));
    thr = d - 40.f;
  }

  float ns[16];
#pragma unroll
  for (int r = 0; r < 16; ++r) ns[r] = 0.f;

  // Staging: thread t slot i covers chunk g = i*512 + t: kh = i*8+wid,
  // col = lane. Source elem offset = col*DIM + kh*8 (per-lane address).
  int srcoff[4];
#pragma unroll
  for (int i = 0; i < 4; ++i) srcoff[i] = lane * DIM + (i * 8 + wid) * 8;
  const int ldsbase = wid * 1024;  // bytes; + i*8192, wave-uniform

  // B-read base: addr = ks*2048 + khalf*1024 + cg*512 + l31*16
  const int boff = khalf * 1024 + cg * 512 + l31 * 16;

  const unsigned short* asrc0 =
      Xb + ((size_t)(strip * APS) * NVIEW + half * 64) * DIM;

  // prologue: stage anchor 0's half-tile into buf[0]
#pragma unroll
  for (int i = 0; i < 4; ++i)
    gload_lds16(asrc0 + srcoff[i], (char*)&buf[0][0] + ldsbase + i * 8192);
  __syncthreads();

  int cb = 0;
  for (int a = 0; a < APS; ++a) {
    if (a + 1 < APS) {
      const unsigned short* src = asrc0 + (size_t)(a + 1) * NVIEW * DIM;
#pragma unroll
      for (int i = 0; i < 4; ++i)
        gload_lds16(src + srcoff[i], (char*)&buf[cb ^ 1][0] + ldsbase + i * 8192);
    }

    const char* bufc = (const char*)&buf[cb][0];
    f32x16 acc = {};
#pragma unroll
    for (int ks = 0; ks < 16; ++ks) {
      bf16x8 bfr = *(const bf16x8*)(bufc + ks * 2048 + boff);
      acc = __builtin_amdgcn_mfma_f32_32x32x16_bf16(afrag[ks], bfr, acc, 0, 0, 0);
    }

    if (slab[strip * APS + a] != myLab) {
      // wave-uniform fast path: all 2048 tile elements underflow exp()
      float vmax = acc[0];
#pragma unroll
      for (int r = 1; r < 16; ++r) vmax = fmaxf(vmax, acc[r]);
      if (__builtin_expect(__any(vmax > thr), 0)) {
#pragma unroll
        for (int r = 0; r < 16; ++r) {
          const int rr = (r & 3) + 8 * (r >> 2) + 4 * khalf;  // row within 32
          float mr = sdiag[rg * 32 + rr];
          float v = acc[r];
          if (v > mr - 40.f) ns[r] += __expf(v - mr);
        }
      }
    }
    __syncthreads();  // staged buffer landed + all reads of buf[cb] done
    cb ^= 1;
  }

  // Reduce ns over the 32 columns (lanes sharing khalf), strides 1..16.
#pragma unroll
  for (int r = 0; r < 16; ++r) {
#pragma unroll
    for (int st = 1; st < 32; st <<= 1) ns[r] += __shfl_xor(ns[r], st);
  }
  if (l31 == 0) {
#pragma unroll
    for (int r = 0; r < 16; ++r) {
      const int rr = (r & 3) + 8 * (r >> 2) + 4 * khalf;
      sns[wid][rr] = ns[r];
    }
  }
  __syncthreads();
  if (tid < 128) {
    const int rg2 = tid >> 5, rr = tid & 31;
    ns_partial[part * N_ROWS + rb * 128 + tid] =
        sns[rg2 * 2 + 0][rr] + sns[rg2 * 2 + 1][rr];
  }
}

// -------- Kernel 3: positives pass. 256 blocks x 32 rows, 8 waves
// (col quarter cq x anchor phase bq), 2 blocks/CU, B from global.
__global__ __launch_bounds__(512, 4) void pcl_pos(
    const unsigned short* __restrict__ Xb, const int* __restrict__ labels,
    const float* __restrict__ diag, const float* __restrict__ ns_partial,
    float* __restrict__ partials) {
  const int blk = blockIdx.x;
  const int r0 = blk * 32;
  const int tid = threadIdx.x;
  const int wid = tid >> 6;
  const int lane = tid & 63;
  const int lo = lane & 15;
  const int hi = lane >> 4;
  const int cq = wid & 3;
  const int bq = wid >> 2;  // 0..1

  __shared__ int slab[NANCH];
  __shared__ float sred[8][32];
  __shared__ float smf[32];
  __shared__ float snsf[32];
  __shared__ int poslist[NANCH];
  __shared__ int scnt;

  if (tid < NANCH) slab[tid] = labels[tid];
  if (tid >= 64 && tid < 96) {
    int r = tid - 64;
    smf[r] = diag[r0 + r];
    float s = 0.f;
#pragma unroll
    for (int p = 0; p < NPART; ++p) s += ns_partial[p * N_ROWS + r0 + r];
    snsf[r] = s;
  }
  if (tid == 0) {
    int La0 = labels[blk >> 2];
    int c = 0;
    for (int b = 0; b < NANCH; ++b)
      if (labels[b] == La0) poslist[c++] = b;
    scnt = c;
  }
  __syncthreads();

  bf16x8 afrag[2][8];
#pragma unroll
  for (int ri = 0; ri < 2; ++ri) {
#pragma unroll
    for (int ks = 0; ks < 8; ++ks) {
      const unsigned short* p = Xb + (r0 + ri * 16 + lo) * DIM + ks * 32 + hi * 8;
      afrag[ri][ks] = *(const bf16x8*)p;
      asm volatile("" : "+v"(afrag[ri][ks]));
    }
  }

  const int cnt = scnt;
  float pos[8];
#pragma unroll
  for (int t = 0; t < 8; ++t) pos[t] = 0.f;

  for (int p = bq; p < cnt; p += 2) {
    const int b = poslist[p];
    const int c0 = b * NVIEW + cq * 32;
    f32x4 acc[2][2];
#pragma unroll
    for (int ri = 0; ri < 2; ++ri)
#pragma unroll
      for (int ci = 0; ci < 2; ++ci)
        acc[ri][ci] = (f32x4){0.f, 0.f, 0.f, 0.f};

#pragma unroll
    for (int ks = 0; ks < 8; ++ks) {
      bf16x8 b0 = *(const bf16x8*)(Xb + (c0 + lo) * DIM + ks * 32 + hi * 8);
      bf16x8 b1 = *(const bf16x8*)(Xb + (c0 + 16 + lo) * DIM + ks * 32 + hi * 8);
      acc[0][0] = __builtin_amdgcn_mfma_f32_16x16x32_bf16(afrag[0][ks], b0, acc[0][0], 0, 0, 0);
      acc[0][1] = __builtin_amdgcn_mfma_f32_16x16x32_bf16(afrag[0][ks], b1, acc[0][1], 0, 0, 0);
      acc[1][0] = __builtin_amdgcn_mfma_f32_16x16x32_bf16(afrag[1][ks], b0, acc[1][0], 0, 0, 0);
      acc[1][1] = __builtin_amdgcn_mfma_f32_16x16x32_bf16(afrag[1][ks], b1, acc[1][1], 0, 0, 0);
    }

#pragma unroll
    for (int ri = 0; ri < 2; ++ri) {
#pragma unroll
      for (int ci = 0; ci < 2; ++ci) {
#pragma unroll
        for (int reg = 0; reg < 4; ++reg) {
          const int t = ri * 4 + reg;
          const int row = ri * 16 + hi * 4 + reg;
          int grow = r0 + row;
          int gcol = c0 + ci * 16 + lo;
          if (grow != gcol) {
            float d = acc[ri][ci][reg] - smf[row];
            pos[t] += d - __logf(__expf(d) + snsf[row] + 1e-10f);
          }
        }
      }
    }
  }

#pragma unroll
  for (int t = 0; t < 8; ++t) {
#pragma unroll
    for (int st = 1; st < 16; st <<= 1) pos[t] += __shfl_xor(pos[t], st);
  }
  if (lo == 0) {
#pragma unroll
    for (int ri = 0; ri < 2; ++ri)
#pragma unroll
      for (int reg = 0; reg < 4; ++reg)
        sred[wid][ri * 16 + hi * 4 + reg] = pos[ri * 4 + reg];
  }
  __syncthreads();

  const float poscnt = (float)(cnt * NVIEW - 1);
  if (tid < 32) {
    float P = 0.f;
#pragma unroll
    for (int w = 0; w < 8; ++w) P += sred[w][tid];
    smf[tid] = P / poscnt;
  }
  __syncthreads();
  if (tid == 0) {
    float s = 0.f;
    for (int r = 0; r < 32; ++r) s += smf[r];
    partials[blk] = s;
  }
}

__global__ void final_reduce(const float* __restrict__ partials, float* __restrict__ out) {
  __shared__ float s[256];
  int t = threadIdx.x;
  s[t] = partials[t];
  __syncthreads();
  for (int st = 128; st > 0; st >>= 1) {
    if (t < st) s[t] += s[t + st];
    __syncthreads();
  }
  if (t == 0) out[0] = -(0.1f / 0.07f) * s[0] / (float)N_ROWS;
}

extern "C" void kernel_launch(void* const* d_in, const int* in_sizes, int n_in,
                              void* d_out, int out_size, void* d_ws, size_t ws_size,
                              hipStream_t stream) {
  const float* feats = (const float*)d_in[0];
  const int* labels = (const int*)d_in[1];
  float* out = (float*)d_out;

  char* base = (char*)d_ws;
  unsigned short* Xb = (unsigned short*)d_ws;                         // 4 MB
  float* diag = (float*)(base + (size_t)N_ROWS * DIM * 2);            // 32 KB
  float* ns_partial = (float*)(base + (size_t)N_ROWS * DIM * 2 + N_ROWS * 4);  // 256 KB
  float* partials = (float*)(base + (size_t)N_ROWS * DIM * 2 + N_ROWS * 4 +
                             NPART * N_ROWS * 4);

  cast_diag_kernel<<<N_ROWS / 4, 256, 0, stream>>>((const float4v*)feats,
                                                   (ushort4v*)Xb, diag);
  pcl_negsum<<<NANCH * NPART, 512, 0, stream>>>(Xb, labels, diag, ns_partial);
  pcl_pos<<<N_ROWS / 32, 512, 0, stream>>>(Xb, labels, diag, ns_partial, partials);
  final_reduce<<<1, 256, 0, stream>>>(partials, out);
}

// Round 7
// 78.294 us; speedup vs baseline: 1.0668x; 1.0668x over previous
//
#include <hip/hip_runtime.h>
#include <hip/hip_bf16.h>

#define N_ROWS 8192
#define DIM 256
#define NANCH 64
#define NVIEW 128
#define APS 16      // anchors per strip
#define NPART 8     // column partitions (4 strips x 2 halves)

typedef __attribute__((ext_vector_type(8))) short bf16x8;
typedef __attribute__((ext_vector_type(4))) float f32x4;
typedef __attribute__((ext_vector_type(16))) float f32x16;
typedef __attribute__((ext_vector_type(4))) float float4v;
typedef __attribute__((ext_vector_type(4))) unsigned short ushort4v;

__device__ __forceinline__ unsigned short f2bf(float x) {
  union { float f; unsigned int u; } c; c.f = x;
  unsigned int u = c.u;
  unsigned int r = (u + 0x7fffu + ((u >> 16) & 1u)) >> 16;
  return (unsigned short)r;
}

__device__ __forceinline__ float bf2f(unsigned short b) {
  union { unsigned int u; float f; } c; c.u = ((unsigned int)b) << 16;
  return c.f;
}

__device__ __forceinline__ void gload_lds16(const void* g, void* l) {
  __builtin_amdgcn_global_load_lds(
      (const __attribute__((address_space(1))) unsigned int*)g,
      (__attribute__((address_space(3))) unsigned int*)l, 16, 0, 0);
}

// fp32 -> bf16 with 1/sqrt(T) prescale, fused with per-row squared-norm
// (= the Gram diagonal = the row max of the logits). One wave per row.
__global__ void cast_diag_kernel(const float4v* __restrict__ in,
                                 ushort4v* __restrict__ out,
                                 float* __restrict__ diag) {
  const int w = threadIdx.x >> 6;
  const int l = threadIdx.x & 63;
  const int row = blockIdx.x * 4 + w;
  const float s = 3.16227766016838f; // 1/sqrt(0.1)
  float4v v = in[row * 64 + l];
  ushort4v o;
  o.x = f2bf(v.x * s);
  o.y = f2bf(v.y * s);
  o.z = f2bf(v.z * s);
  o.w = f2bf(v.w * s);
  out[row * 64 + l] = o;
  float c0 = bf2f(o.x), c1 = bf2f(o.y), c2 = bf2f(o.z), c3 = bf2f(o.w);
  float ss = c0 * c0 + c1 * c1 + c2 * c2 + c3 * c3;
#pragma unroll
  for (int st = 1; st < 64; st <<= 1) ss += __shfl_xor(ss, st);
  if (l == 0) diag[row] = ss;
}

// -------- Kernel 2: negative-exp-sum partials over (128 rows x 1024 cols).
// grid = 64 row-blocks x 8 col-partitions, 256 threads = 4 waves (2 row-
// groups x 2 col-groups), each wave owns 64 rows x 32 cols: one B-fragment
// read feeds TWO 32x32x16 MFMAs (LDS reads halve vs round 6 -> MFMA-bound),
// and each row-tile uses two half-K accumulators -> 4 independent MFMA
// chains of depth 8 (round-6's single depth-16 chain starved the pipe).
// B staged in k-major LDS layout [k-octet 0..31][col 0..63][16B]: wave reads
// are contiguous 512B segments -> structurally zero bank conflicts.
// Row max is KNOWN (= diag): partials combine by pure addition.
__global__ __launch_bounds__(256, 2) void pcl_negsum(
    const unsigned short* __restrict__ Xb, const int* __restrict__ labels,
    const float* __restrict__ diag, float* __restrict__ ns_partial) {
  const int rb = blockIdx.x & 63;       // row anchor (128 rows, uniform label)
  const int part = blockIdx.x >> 6;     // 0..7
  const int strip = part >> 1;          // anchors strip*16 .. +15
  const int half = part & 1;            // 64-col half within each anchor
  const int tid = threadIdx.x;          // 0..255
  const int wid = tid >> 6;             // 0..3
  const int lane = tid & 63;
  const int l31 = lane & 31;
  const int khalf = lane >> 5;          // k-octet half within fragment
  const int rg = wid >> 1;              // row group (64 rows)
  const int cg = wid & 1;               // col group (32 cols)

  __shared__ __align__(16) unsigned short buf[2][64 * DIM];  // 2 x 32 KB
  __shared__ float sdiag[128];
  __shared__ float nsacc[128];
  __shared__ int slab[NANCH];

  if (tid < NANCH) slab[tid] = labels[tid];
  if (tid < 128) nsacc[tid] = 0.f;
  if (tid >= 128) sdiag[tid - 128] = diag[rb * 128 + tid - 128];
  __syncthreads();
  const int myLab = slab[rb];

  // A fragments: 2 row-tiles; lane holds row rg*64 + ri*32 + l31,
  // k = ks*16 + khalf*8 .. +8.
  bf16x8 afrag[2][16];
#pragma unroll
  for (int ri = 0; ri < 2; ++ri) {
#pragma unroll
    for (int ks = 0; ks < 16; ++ks) {
      const unsigned short* p =
          Xb + (size_t)(rb * 128 + rg * 64 + ri * 32 + l31) * DIM + ks * 16 + khalf * 8;
      afrag[ri][ks] = *(const bf16x8*)p;
      asm volatile("" : "+v"(afrag[ri][ks]));  // def-pin: forbid remat
    }
  }

  // Wave-uniform skip threshold: min diag over this wave's 64 rows - 40.
  float thr;
  {
    float d = sdiag[rg * 64 + lane];
#pragma unroll
    for (int st = 1; st < 64; st <<= 1) d = fminf(d, __shfl_xor(d, st));
    thr = d - 40.f;
  }

  // Staging: thread covers chunks g = i*256 + tid (i=0..7): k-octet = i*4+wid,
  // col = lane. LDS dest wave-uniform base + lane*16; global src per-lane.
  const int srcbase = lane * DIM + wid * 8;  // + i*32 elements
  const unsigned short* asrc0 =
      Xb + ((size_t)(strip * APS) * NVIEW + half * 64) * DIM;

  // prologue: stage anchor 0's half-tile into buf[0]
#pragma unroll
  for (int i = 0; i < 8; ++i)
    gload_lds16(asrc0 + srcbase + i * 32, (char*)&buf[0][0] + wid * 1024 + i * 4096);
  __syncthreads();

  // B-read: col = cg*32 + l31, k-octet = ks*2 + khalf
  const int boff = khalf * 1024 + cg * 512 + l31 * 16;

  int cb = 0;
  for (int a = 0; a < APS; ++a) {
    if (a + 1 < APS) {
      const unsigned short* src = asrc0 + (size_t)(a + 1) * NVIEW * DIM;
#pragma unroll
      for (int i = 0; i < 8; ++i)
        gload_lds16(src + srcbase + i * 32, (char*)&buf[cb ^ 1][0] + wid * 1024 + i * 4096);
    }

    const char* bufc = (const char*)&buf[cb][0];
    f32x16 a0A = {}, a0B = {}, a1A = {}, a1B = {};  // 4 independent chains
#pragma unroll
    for (int ks = 0; ks < 16; ++ks) {
      bf16x8 bfr = *(const bf16x8*)(bufc + ks * 2048 + boff);
      if (ks < 8) {
        a0A = __builtin_amdgcn_mfma_f32_32x32x16_bf16(afrag[0][ks], bfr, a0A, 0, 0, 0);
        a1A = __builtin_amdgcn_mfma_f32_32x32x16_bf16(afrag[1][ks], bfr, a1A, 0, 0, 0);
      } else {
        a0B = __builtin_amdgcn_mfma_f32_32x32x16_bf16(afrag[0][ks], bfr, a0B, 0, 0, 0);
        a1B = __builtin_amdgcn_mfma_f32_32x32x16_bf16(afrag[1][ks], bfr, a1B, 0, 0, 0);
      }
    }

    if (slab[strip * APS + a] != myLab) {
      f32x16 c0 = a0A + a0B;
      f32x16 c1 = a1A + a1B;
      float vmax = c0[0];
#pragma unroll
      for (int r = 1; r < 16; ++r) vmax = fmaxf(vmax, c0[r]);
#pragma unroll
      for (int r = 0; r < 16; ++r) vmax = fmaxf(vmax, c1[r]);
      // fast path: entire 64x32 tile underflows exp() (error < e^-40 * N << eps)
      if (__builtin_expect(__any(vmax > thr), 0)) {
#pragma unroll
        for (int t2 = 0; t2 < 2; ++t2) {
#pragma unroll
          for (int r = 0; r < 16; ++r) {
            const int rloc = (r & 3) + 8 * (r >> 2) + 4 * khalf;
            const int row = rg * 64 + t2 * 32 + rloc;
            float v = t2 ? c1[r] : c0[r];
            float mr = sdiag[row];
            float e = (v > mr - 40.f) ? __expf(v - mr) : 0.f;
#pragma unroll
            for (int st = 1; st < 32; st <<= 1) e += __shfl_xor(e, st);
            if (l31 == 0) atomicAdd(&nsacc[row], e);
          }
        }
      }
    }
    __syncthreads();  // staged buffer landed + all reads of buf[cb] done
    cb ^= 1;
  }

  if (tid < 128)
    ns_partial[part * N_ROWS + rb * 128 + tid] = nsacc[tid];
}

// -------- Kernel 3: positives pass. 256 blocks x 32 rows, 8 waves
// (col quarter cq x anchor phase bq), 2 blocks/CU, B from global.
// Epilogue fast path: d < -45 -> log(exp(d)+NS+eps) == log(NS+eps) to 3e-10,
// which is a per-row constant (precomputed) -> 3 VALU per element.
__global__ __launch_bounds__(512, 4) void pcl_pos(
    const unsigned short* __restrict__ Xb, const int* __restrict__ labels,
    const float* __restrict__ diag, const float* __restrict__ ns_partial,
    float* __restrict__ partials) {
  const int blk = blockIdx.x;
  const int r0 = blk * 32;
  const int tid = threadIdx.x;
  const int wid = tid >> 6;
  const int lane = tid & 63;
  const int lo = lane & 15;
  const int hi = lane >> 4;
  const int cq = wid & 3;
  const int bq = wid >> 2;  // 0..1

  __shared__ int slab[NANCH];
  __shared__ float sred[8][32];
  __shared__ float smf[32];
  __shared__ float snsf[32];
  __shared__ float slog[32];
  __shared__ int poslist[NANCH];
  __shared__ int scnt;

  if (tid < NANCH) slab[tid] = labels[tid];
  if (tid >= 64 && tid < 96) {
    int r = tid - 64;
    smf[r] = diag[r0 + r];
    float s = 0.f;
#pragma unroll
    for (int p = 0; p < NPART; ++p) s += ns_partial[p * N_ROWS + r0 + r];
    snsf[r] = s;
    slog[r] = __logf(s + 1e-10f);
  }
  if (tid == 0) {
    int La0 = labels[blk >> 2];
    int c = 0;
    for (int b = 0; b < NANCH; ++b)
      if (labels[b] == La0) poslist[c++] = b;
    scnt = c;
  }
  __syncthreads();

  bf16x8 afrag[2][8];
#pragma unroll
  for (int ri = 0; ri < 2; ++ri) {
#pragma unroll
    for (int ks = 0; ks < 8; ++ks) {
      const unsigned short* p = Xb + (r0 + ri * 16 + lo) * DIM + ks * 32 + hi * 8;
      afrag[ri][ks] = *(const bf16x8*)p;
      asm volatile("" : "+v"(afrag[ri][ks]));
    }
  }

  const int cnt = scnt;
  float pos[8];
#pragma unroll
  for (int t = 0; t < 8; ++t) pos[t] = 0.f;

  for (int p = bq; p < cnt; p += 2) {
    const int b = poslist[p];
    const int c0 = b * NVIEW + cq * 32;
    f32x4 acc[2][2];
#pragma unroll
    for (int ri = 0; ri < 2; ++ri)
#pragma unroll
      for (int ci = 0; ci < 2; ++ci)
        acc[ri][ci] = (f32x4){0.f, 0.f, 0.f, 0.f};

#pragma unroll
    for (int ks = 0; ks < 8; ++ks) {
      bf16x8 b0 = *(const bf16x8*)(Xb + (c0 + lo) * DIM + ks * 32 + hi * 8);
      bf16x8 b1 = *(const bf16x8*)(Xb + (c0 + 16 + lo) * DIM + ks * 32 + hi * 8);
      acc[0][0] = __builtin_amdgcn_mfma_f32_16x16x32_bf16(afrag[0][ks], b0, acc[0][0], 0, 0, 0);
      acc[0][1] = __builtin_amdgcn_mfma_f32_16x16x32_bf16(afrag[0][ks], b1, acc[0][1], 0, 0, 0);
      acc[1][0] = __builtin_amdgcn_mfma_f32_16x16x32_bf16(afrag[1][ks], b0, acc[1][0], 0, 0, 0);
      acc[1][1] = __builtin_amdgcn_mfma_f32_16x16x32_bf16(afrag[1][ks], b1, acc[1][1], 0, 0, 0);
    }

#pragma unroll
    for (int ri = 0; ri < 2; ++ri) {
#pragma unroll
      for (int ci = 0; ci < 2; ++ci) {
#pragma unroll
        for (int reg = 0; reg < 4; ++reg) {
          const int t = ri * 4 + reg;
          const int row = ri * 16 + hi * 4 + reg;
          int grow = r0 + row;
          int gcol = c0 + ci * 16 + lo;
          if (grow != gcol) {
            float d = acc[ri][ci][reg] - smf[row];
            float lp;
            if (__builtin_expect(d > -45.f, 0))
              lp = d - __logf(__expf(d) + snsf[row] + 1e-10f);  // exact
            else
              lp = d - slog[row];  // exp(d) negligible vs eps floor
            pos[t] += lp;
          }
        }
      }
    }
  }

#pragma unroll
  for (int t = 0; t < 8; ++t) {
#pragma unroll
    for (int st = 1; st < 16; st <<= 1) pos[t] += __shfl_xor(pos[t], st);
  }
  if (lo == 0) {
#pragma unroll
    for (int ri = 0; ri < 2; ++ri)
#pragma unroll
      for (int reg = 0; reg < 4; ++reg)
        sred[wid][ri * 16 + hi * 4 + reg] = pos[ri * 4 + reg];
  }
  __syncthreads();

  const float poscnt = (float)(cnt * NVIEW - 1);
  if (tid < 32) {
    float P = 0.f;
#pragma unroll
    for (int w = 0; w < 8; ++w) P += sred[w][tid];
    smf[tid] = P / poscnt;
  }
  __syncthreads();
  if (tid == 0) {
    float s = 0.f;
    for (int r = 0; r < 32; ++r) s += smf[r];
    partials[blk] = s;
  }
}

__global__ void final_reduce(const float* __restrict__ partials, float* __restrict__ out) {
  __shared__ float s[256];
  int t = threadIdx.x;
  s[t] = partials[t];
  __syncthreads();
  for (int st = 128; st > 0; st >>= 1) {
    if (t < st) s[t] += s[t + st];
    __syncthreads();
  }
  if (t == 0) out[0] = -(0.1f / 0.07f) * s[0] / (float)N_ROWS;
}

extern "C" void kernel_launch(void* const* d_in, const int* in_sizes, int n_in,
                              void* d_out, int out_size, void* d_ws, size_t ws_size,
                              hipStream_t stream) {
  const float* feats = (const float*)d_in[0];
  const int* labels = (const int*)d_in[1];
  float* out = (float*)d_out;

  char* base = (char*)d_ws;
  unsigned short* Xb = (unsigned short*)d_ws;                         // 4 MB
  float* diag = (float*)(base + (size_t)N_ROWS * DIM * 2);            // 32 KB
  float* ns_partial = (float*)(base + (size_t)N_ROWS * DIM * 2 + N_ROWS * 4);  // 256 KB
  float* partials = (float*)(base + (size_t)N_ROWS * DIM * 2 + N_ROWS * 4 +
                             NPART * N_ROWS * 4);

  cast_diag_kernel<<<N_ROWS / 4, 256, 0, stream>>>((const float4v*)feats,
                                                   (ushort4v*)Xb, diag);
  pcl_negsum<<<NANCH * NPART, 256, 0, stream>>>(Xb, labels, diag, ns_partial);
  pcl_pos<<<N_ROWS / 32, 512, 0, stream>>>(Xb, labels, diag, ns_partial, partials);
  final_reduce<<<1, 256, 0, stream>>>(partials, out);
}

// Round 8
// 75.348 us; speedup vs baseline: 1.1085x; 1.0391x over previous
//
#include <hip/hip_runtime.h>
#include <hip/hip_bf16.h>

#define N_ROWS 8192
#define DIM 256
#define NANCH 64
#define NVIEW 128
#define NPART 8     // column partitions (8 anchors = 1024 cols each)

typedef __attribute__((ext_vector_type(8))) short bf16x8;
typedef __attribute__((ext_vector_type(4))) float f32x4;
typedef __attribute__((ext_vector_type(16))) float f32x16;
typedef __attribute__((ext_vector_type(4))) float float4v;
typedef __attribute__((ext_vector_type(4))) unsigned short ushort4v;

__device__ __forceinline__ unsigned short f2bf(float x) {
  union { float f; unsigned int u; } c; c.f = x;
  unsigned int u = c.u;
  unsigned int r = (u + 0x7fffu + ((u >> 16) & 1u)) >> 16;
  return (unsigned short)r;
}

__device__ __forceinline__ float bf2f(unsigned short b) {
  union { unsigned int u; float f; } c; c.u = ((unsigned int)b) << 16;
  return c.f;
}

__device__ __forceinline__ void gload_lds16(const void* g, void* l) {
  __builtin_amdgcn_global_load_lds(
      (const __attribute__((address_space(1))) unsigned int*)g,
      (__attribute__((address_space(3))) unsigned int*)l, 16, 0, 0);
}

// fp32 -> bf16 with 1/sqrt(T) prescale, fused with per-row squared-norm
// (= the Gram diagonal = the row max of the logits). One wave per row.
__global__ void cast_diag_kernel(const float4v* __restrict__ in,
                                 ushort4v* __restrict__ out,
                                 float* __restrict__ diag) {
  const int w = threadIdx.x >> 6;
  const int l = threadIdx.x & 63;
  const int row = blockIdx.x * 4 + w;
  const float s = 3.16227766016838f; // 1/sqrt(0.1)
  float4v v = in[row * 64 + l];
  ushort4v o;
  o.x = f2bf(v.x * s);
  o.y = f2bf(v.y * s);
  o.z = f2bf(v.z * s);
  o.w = f2bf(v.w * s);
  out[row * 64 + l] = o;
  float c0 = bf2f(o.x), c1 = bf2f(o.y), c2 = bf2f(o.z), c3 = bf2f(o.w);
  float ss = c0 * c0 + c1 * c1 + c2 * c2 + c3 * c3;
#pragma unroll
  for (int st = 1; st < 64; st <<= 1) ss += __shfl_xor(ss, st);
  if (l == 0) diag[row] = ss;
}

// -------- Kernel 2: negative-exp-sum over (256 rows x 1024 cols) per block.
// grid = 32 row-pair-blocks x 8 parts, 512 threads = 8 waves (4 row-groups x
// 2 col-groups), 1 block/CU. Streams 16 half-anchor tiles (64 cols x K=256,
// 32 KB, k-major conflict-free layout) through a 4-slot LDS ring staged
// 3-deep ahead with global_load_lds. T3+T4 schedule: raw s_barrier + COUNTED
// vmcnt (12/8/4/0, never 0 mid-loop) so staging stays in flight across
// barriers -- no __syncthreads-induced vmcnt(0) drain in the loop.
// Row max is KNOWN (= diag): partials combine by pure addition.
__global__ __launch_bounds__(512, 2) void pcl_negsum(
    const unsigned short* __restrict__ Xb, const int* __restrict__ labels,
    const float* __restrict__ diag, float* __restrict__ ns_partial) {
  const int bx = blockIdx.x;
  const int rbp = bx & 31;            // rows rbp*256 .. +255 (2 row-anchors)
  const int part = bx >> 5;           // 0..7 -> col anchors part*8 .. +7
  const int abase = part * 8;
  const int tid = threadIdx.x;
  const int wid = tid >> 6;           // 0..7
  const int lane = tid & 63;
  const int l31 = lane & 31;
  const int khalf = lane >> 5;
  const int rg = wid >> 1;            // row group (64 rows)
  const int cg = wid & 1;             // col group (32 cols)
  const int R0 = rbp * 256;

  __shared__ __align__(16) unsigned short ring[4 * 64 * DIM];  // 4 x 32 KB
  __shared__ float sdiag[256];
  __shared__ float nsacc[256];
  __shared__ int slab[NANCH];

  if (tid < NANCH) slab[tid] = labels[tid];
  if (tid < 256) { sdiag[tid] = diag[R0 + tid]; nsacc[tid] = 0.f; }
  __syncthreads();
  const int myLab = slab[rbp * 2 + (rg >> 1)];

  // A fragments: lane holds row R0 + rg*64 + ri*32 + l31, k = ks*16+khalf*8.
  // The "+v" pins force materialization (and drain the A-load vmcnt before
  // staging starts, keeping the counted-vmcnt bookkeeping exact).
  bf16x8 afrag[2][16];
#pragma unroll
  for (int ri = 0; ri < 2; ++ri) {
#pragma unroll
    for (int ks = 0; ks < 16; ++ks) {
      const unsigned short* p =
          Xb + (size_t)(R0 + rg * 64 + ri * 32 + l31) * DIM + ks * 16 + khalf * 8;
      afrag[ri][ks] = *(const bf16x8*)p;
    }
  }
#pragma unroll
  for (int ri = 0; ri < 2; ++ri)
#pragma unroll
    for (int ks = 0; ks < 16; ++ks) asm volatile("" : "+v"(afrag[ri][ks]));

  // Wave-uniform skip threshold: min diag over this wave's 64 rows - 40.
  float thr;
  {
    float d = sdiag[rg * 64 + lane];
#pragma unroll
    for (int st = 1; st < 64; st <<= 1) d = fminf(d, __shfl_xor(d, st));
    thr = d - 40.f;
  }

  char* const L0 = (char*)&ring[0];

  // Stage half-tile H (H=0..15: anchor abase+(H>>1), col-half H&1) into slot
  // H&3. Thread covers chunks g = i*512+tid: k-octet = i*8+wid, col = lane.
#define STAGE(H)                                                                \
  do {                                                                          \
    const unsigned short* _s =                                                  \
        Xb + (size_t)((abase + ((H) >> 1)) * NVIEW + ((H) & 1) * 64 + lane) *   \
                 DIM + wid * 8;                                                 \
    char* _d = L0 + ((H) & 3) * 32768 + wid * 1024;                             \
    gload_lds16(_s, _d);                                                        \
    gload_lds16(_s + 64, _d + 8192);                                            \
    gload_lds16(_s + 128, _d + 16384);                                          \
    gload_lds16(_s + 192, _d + 24576);                                          \
  } while (0)

  STAGE(0);
  STAGE(1);
  STAGE(2);

#define ITER(S, VN)                                                             \
  do {                                                                          \
    if ((S) + 3 < 16) STAGE((S) + 3);                                           \
    asm volatile("s_waitcnt vmcnt(" #VN ")");                                   \
    __builtin_amdgcn_sched_barrier(0);                                          \
    __builtin_amdgcn_s_barrier();                                               \
    __builtin_amdgcn_sched_barrier(0);                                          \
    const char* _sb =                                                           \
        L0 + ((S) & 3) * 32768 + khalf * 1024 + cg * 512 + l31 * 16;            \
    f32x16 a0A = {}, a0B = {}, a1A = {}, a1B = {};                              \
    __builtin_amdgcn_s_setprio(1);                                              \
    _Pragma("unroll") for (int ks = 0; ks < 8; ++ks) {                          \
      bf16x8 b0 = *(const bf16x8*)(_sb + ks * 2048);                            \
      bf16x8 b1 = *(const bf16x8*)(_sb + (ks + 8) * 2048);                      \
      a0A = __builtin_amdgcn_mfma_f32_32x32x16_bf16(afrag[0][ks], b0, a0A, 0, 0, 0); \
      a1A = __builtin_amdgcn_mfma_f32_32x32x16_bf16(afrag[1][ks], b0, a1A, 0, 0, 0); \
      a0B = __builtin_amdgcn_mfma_f32_32x32x16_bf16(afrag[0][ks + 8], b1, a0B, 0, 0, 0); \
      a1B = __builtin_amdgcn_mfma_f32_32x32x16_bf16(afrag[1][ks + 8], b1, a1B, 0, 0, 0); \
    }                                                                           \
    __builtin_amdgcn_s_setprio(0);                                              \
    if (slab[abase + ((S) >> 1)] != myLab) {                                    \
      f32x16 c0 = a0A + a0B;                                                    \
      f32x16 c1 = a1A + a1B;                                                    \
      float vmax = fmaxf(c0[0], c1[0]);                                         \
      _Pragma("unroll") for (int r = 1; r < 16; ++r)                            \
          vmax = fmaxf(vmax, fmaxf(c0[r], c1[r]));                              \
      if (__builtin_expect(__any(vmax > thr), 0)) {                             \
        _Pragma("unroll") for (int t2 = 0; t2 < 2; ++t2) {                      \
          _Pragma("unroll") for (int r = 0; r < 16; ++r) {                      \
            const int rloc = (r & 3) + 8 * (r >> 2) + 4 * khalf;                \
            const int row = rg * 64 + t2 * 32 + rloc;                           \
            float v = t2 ? c1[r] : c0[r];                                       \
            float mr = sdiag[row];                                              \
            float e = (v > mr - 40.f) ? __expf(v - mr) : 0.f;                   \
            _Pragma("unroll") for (int st = 1; st < 32; st <<= 1)               \
                e += __shfl_xor(e, st);                                         \
            if (l31 == 0) atomicAdd(&nsacc[row], e);                            \
          }                                                                     \
        }                                                                       \
      }                                                                         \
    }                                                                           \
    __builtin_amdgcn_s_barrier();                                               \
  } while (0)

  ITER(0, 12);  ITER(1, 12);  ITER(2, 12);  ITER(3, 12);
  ITER(4, 12);  ITER(5, 12);  ITER(6, 12);  ITER(7, 12);
  ITER(8, 12);  ITER(9, 12);  ITER(10, 12); ITER(11, 12);
  ITER(12, 12); ITER(13, 8);  ITER(14, 4);  ITER(15, 0);

#undef ITER
#undef STAGE

  __syncthreads();
  if (tid < 256) ns_partial[part * N_ROWS + R0 + tid] = nsacc[tid];
}

// -------- Kernel 3: positives pass. 256 blocks x 32 rows, 8 waves
// (col quarter cq x anchor phase bq), 2 blocks/CU, B from global.
// Epilogue fast path: d < -45 -> log(exp(d)+NS+eps) == log(NS+eps) to 3e-10,
// which is a per-row constant (precomputed) -> 3 VALU per element.
__global__ __launch_bounds__(512, 4) void pcl_pos(
    const unsigned short* __restrict__ Xb, const int* __restrict__ labels,
    const float* __restrict__ diag, const float* __restrict__ ns_partial,
    float* __restrict__ partials) {
  const int blk = blockIdx.x;
  const int r0 = blk * 32;
  const int tid = threadIdx.x;
  const int wid = tid >> 6;
  const int lane = tid & 63;
  const int lo = lane & 15;
  const int hi = lane >> 4;
  const int cq = wid & 3;
  const int bq = wid >> 2;  // 0..1

  __shared__ int slab[NANCH];
  __shared__ float sred[8][32];
  __shared__ float smf[32];
  __shared__ float snsf[32];
  __shared__ float slog[32];
  __shared__ int poslist[NANCH];
  __shared__ int scnt;

  if (tid < NANCH) slab[tid] = labels[tid];
  if (tid >= 64 && tid < 96) {
    int r = tid - 64;
    smf[r] = diag[r0 + r];
    float s = 0.f;
#pragma unroll
    for (int p = 0; p < NPART; ++p) s += ns_partial[p * N_ROWS + r0 + r];
    snsf[r] = s;
    slog[r] = __logf(s + 1e-10f);
  }
  if (tid == 0) {
    int La0 = labels[blk >> 2];
    int c = 0;
    for (int b = 0; b < NANCH; ++b)
      if (labels[b] == La0) poslist[c++] = b;
    scnt = c;
  }
  __syncthreads();

  bf16x8 afrag[2][8];
#pragma unroll
  for (int ri = 0; ri < 2; ++ri) {
#pragma unroll
    for (int ks = 0; ks < 8; ++ks) {
      const unsigned short* p = Xb + (r0 + ri * 16 + lo) * DIM + ks * 32 + hi * 8;
      afrag[ri][ks] = *(const bf16x8*)p;
      asm volatile("" : "+v"(afrag[ri][ks]));
    }
  }

  const int cnt = scnt;
  float pos[8];
#pragma unroll
  for (int t = 0; t < 8; ++t) pos[t] = 0.f;

  for (int p = bq; p < cnt; p += 2) {
    const int b = poslist[p];
    const int c0 = b * NVIEW + cq * 32;
    f32x4 acc[2][2];
#pragma unroll
    for (int ri = 0; ri < 2; ++ri)
#pragma unroll
      for (int ci = 0; ci < 2; ++ci)
        acc[ri][ci] = (f32x4){0.f, 0.f, 0.f, 0.f};

#pragma unroll
    for (int ks = 0; ks < 8; ++ks) {
      bf16x8 b0 = *(const bf16x8*)(Xb + (c0 + lo) * DIM + ks * 32 + hi * 8);
      bf16x8 b1 = *(const bf16x8*)(Xb + (c0 + 16 + lo) * DIM + ks * 32 + hi * 8);
      acc[0][0] = __builtin_amdgcn_mfma_f32_16x16x32_bf16(afrag[0][ks], b0, acc[0][0], 0, 0, 0);
      acc[0][1] = __builtin_amdgcn_mfma_f32_16x16x32_bf16(afrag[0][ks], b1, acc[0][1], 0, 0, 0);
      acc[1][0] = __builtin_amdgcn_mfma_f32_16x16x32_bf16(afrag[1][ks], b0, acc[1][0], 0, 0, 0);
      acc[1][1] = __builtin_amdgcn_mfma_f32_16x16x32_bf16(afrag[1][ks], b1, acc[1][1], 0, 0, 0);
    }

#pragma unroll
    for (int ri = 0; ri < 2; ++ri) {
#pragma unroll
      for (int ci = 0; ci < 2; ++ci) {
#pragma unroll
        for (int reg = 0; reg < 4; ++reg) {
          const int t = ri * 4 + reg;
          const int row = ri * 16 + hi * 4 + reg;
          int grow = r0 + row;
          int gcol = c0 + ci * 16 + lo;
          if (grow != gcol) {
            float d = acc[ri][ci][reg] - smf[row];
            float lp;
            if (__builtin_expect(d > -45.f, 0))
              lp = d - __logf(__expf(d) + snsf[row] + 1e-10f);  // exact
            else
              lp = d - slog[row];  // exp(d) negligible vs eps floor
            pos[t] += lp;
          }
        }
      }
    }
  }

#pragma unroll
  for (int t = 0; t < 8; ++t) {
#pragma unroll
    for (int st = 1; st < 16; st <<= 1) pos[t] += __shfl_xor(pos[t], st);
  }
  if (lo == 0) {
#pragma unroll
    for (int ri = 0; ri < 2; ++ri)
#pragma unroll
      for (int reg = 0; reg < 4; ++reg)
        sred[wid][ri * 16 + hi * 4 + reg] = pos[ri * 4 + reg];
  }
  __syncthreads();

  const float poscnt = (float)(cnt * NVIEW - 1);
  if (tid < 32) {
    float P = 0.f;
#pragma unroll
    for (int w = 0; w < 8; ++w) P += sred[w][tid];
    smf[tid] = P / poscnt;
  }
  __syncthreads();
  if (tid == 0) {
    float s = 0.f;
    for (int r = 0; r < 32; ++r) s += smf[r];
    partials[blk] = s;
  }
}

__global__ void final_reduce(const float* __restrict__ partials, float* __restrict__ out) {
  __shared__ float s[256];
  int t = threadIdx.x;
  s[t] = partials[t];
  __syncthreads();
  for (int st = 128; st > 0; st >>= 1) {
    if (t < st) s[t] += s[t + st];
    __syncthreads();
  }
  if (t == 0) out[0] = -(0.1f / 0.07f) * s[0] / (float)N_ROWS;
}

extern "C" void kernel_launch(void* const* d_in, const int* in_sizes, int n_in,
                              void* d_out, int out_size, void* d_ws, size_t ws_size,
                              hipStream_t stream) {
  const float* feats = (const float*)d_in[0];
  const int* labels = (const int*)d_in[1];
  float* out = (float*)d_out;

  char* base = (char*)d_ws;
  unsigned short* Xb = (unsigned short*)d_ws;                         // 4 MB
  float* diag = (float*)(base + (size_t)N_ROWS * DIM * 2);            // 32 KB
  float* ns_partial = (float*)(base + (size_t)N_ROWS * DIM * 2 + N_ROWS * 4);  // 256 KB
  float* partials = (float*)(base + (size_t)N_ROWS * DIM * 2 + N_ROWS * 4 +
                             NPART * N_ROWS * 4);

  cast_diag_kernel<<<N_ROWS / 4, 256, 0, stream>>>((const float4v*)feats,
                                                   (ushort4v*)Xb, diag);
  pcl_negsum<<<32 * NPART, 512, 0, stream>>>(Xb, labels, diag, ns_partial);
  pcl_pos<<<N_ROWS / 32, 512, 0, stream>>>(Xb, labels, diag, ns_partial, partials);
  final_reduce<<<1, 256, 0, stream>>>(partials, out);
}